// Round 9
// baseline (358.939 us; speedup 1.0000x reference)
//
#include <hip/hip_runtime.h>

// SLAYER 3-layer CUBA SNN — fused MFMA GEMM + leaky-IF scan (4 launches).
// R9: back to proven R7 structure (cooperative single-kernel failed R8).
// GEMM change: A-fragments are loaded DIRECTLY from global (16B/lane
// global_load_dwordx4) instead of staging through LDS — halves LDS traffic
// (was 96 KB/chunk/block, the binding resource at MfmaUtil 41%). Only B hi/lo
// planes are staged via glds16 + XOR slot swizzle (proven conflict-free).
// Weights: W = hi + lo bf16 planes; spikes exact in bf16 (absmax 0.0 R3-R7).
// Layout m = b*128 + t: block holds full Z[t][o] history -> in-LDS scan.

typedef unsigned short ushort_t;
typedef unsigned int uint_t;
typedef __bf16 bf16x8 __attribute__((ext_vector_type(8)));
typedef float f32x4 __attribute__((ext_vector_type(4)));

#define O_TOT 1024

__device__ __forceinline__ void glds16(const ushort_t* g, ushort_t* l) {
  __builtin_amdgcn_global_load_lds(
      (const __attribute__((address_space(1))) uint_t*)g,
      (__attribute__((address_space(3))) uint_t*)l, 16, 0, 0);
}

__device__ __forceinline__ ushort_t f32_to_bf16_rne(float f) {
  uint_t u = __float_as_uint(f);
  u += 0x7FFFu + ((u >> 16) & 1u);
  return (ushort_t)(u >> 16);
}

// ---- prep: W1/W2 hi-lo split (blocks 0..12287) + spike transpose (rest) ----
__global__ __launch_bounds__(256) void prep(const float* __restrict__ W1,
                                            const float* __restrict__ W2,
                                            const float* __restrict__ spike,
                                            ushort_t* __restrict__ h1,
                                            ushort_t* __restrict__ l1,
                                            ushort_t* __restrict__ h2,
                                            ushort_t* __restrict__ l2,
                                            ushort_t* __restrict__ A1) {
  const int tid = threadIdx.x;
  if (blockIdx.x < 12288) {
    int idx = blockIdx.x * 256 + tid;
    const int N1 = 1024 * 2048;
    if (idx < N1) {
      float w = W1[idx];
      ushort_t h = f32_to_bf16_rne(w);
      h1[idx] = h;
      l1[idx] = f32_to_bf16_rne(w - __uint_as_float(((uint_t)h) << 16));
    } else {
      int k = idx - N1;
      float w = W2[k];
      ushort_t h = f32_to_bf16_rne(w);
      h2[k] = h;
      l2[k] = f32_to_bf16_rne(w - __uint_as_float(((uint_t)h) << 16));
    }
    return;
  }
  __shared__ ushort_t lds[128 * 130];  // [i][t] padded, 33,280 B
  const int bid = blockIdx.x - 12288;  // 0..1023
  const int b = bid >> 4;
  const int i0 = (bid & 15) * 128;
#pragma unroll
  for (int it = 0; it < 16; ++it) {
    int p = it * 256 + tid;
    int i = p >> 5, tg = (p & 31) * 4;
    float4 v = *(const float4*)(spike + ((size_t)b * 2048 + i0 + i) * 128 + tg);
    lds[i * 130 + tg + 0] = (v.x != 0.0f) ? 0x3F80u : 0u;
    lds[i * 130 + tg + 1] = (v.y != 0.0f) ? 0x3F80u : 0u;
    lds[i * 130 + tg + 2] = (v.z != 0.0f) ? 0x3F80u : 0u;
    lds[i * 130 + tg + 3] = (v.w != 0.0f) ? 0x3F80u : 0u;
  }
  __syncthreads();
#pragma unroll
  for (int it = 0; it < 16; ++it) {
    int p = it * 256 + tid;
    int t = p >> 5, j = p & 31;  // j: uint2 index (4 ushorts)
    uint_t u0 = (uint_t)lds[(4 * j + 0) * 130 + t] | ((uint_t)lds[(4 * j + 1) * 130 + t] << 16);
    uint_t u1 = (uint_t)lds[(4 * j + 2) * 130 + t] | ((uint_t)lds[(4 * j + 3) * 130 + t] << 16);
    uint2* dst = (uint2*)(A1 + (size_t)(b * 128 + t) * 2048 + i0);
    dst[j] = make_uint2(u0, u1);
  }
}

// ------- fused GEMM (128m x 64o tile, kc64, hi/lo bf16) + scan --------------
// B planes staged in LDS (XOR slot swizzle: slot(row,u) = row*8 + (u^(row&7)));
// A frags loaded straight from global (16B/lane, L1-backed, 2x reuse per CU).
__global__ __launch_bounds__(256, 4)
void gemm_scan(const ushort_t* __restrict__ A, const ushort_t* __restrict__ Bhi,
               const ushort_t* __restrict__ Blo, ushort_t* __restrict__ S,
               int K) {
  __shared__ float smemf[128 * 65];   // 33,280 B (Zt epilogue overlay)
  ushort_t* Bh = (ushort_t*)smemf;    // 64 x 64 (8 KB)
  ushort_t* Bl = Bh + 4096;           // 8 KB
  float* Zt = smemf;                  // [128 t][65]

  const int tid = threadIdx.x;
  const int wave = tid >> 6, lane = tid & 63;
  const int b = blockIdx.y;
  const int m0 = b * 128;
  const int o0 = blockIdx.x * 64;
  const int qm = wave >> 1, qn = wave & 1;
  const int fr = lane & 15, q = lane >> 4;

  f32x4 acc[4][2];
#pragma unroll
  for (int i = 0; i < 4; ++i)
#pragma unroll
    for (int j = 0; j < 2; ++j) acc[i][j] = (f32x4){0.f, 0.f, 0.f, 0.f};

  // B staging: 512 slots/plane, 2 rounds/wave.
  size_t gB[2];
  ushort_t *lBh[2], *lBl[2];
#pragma unroll
  for (int r = 0; r < 2; ++r) {
    int s = wave * 128 + r * 64 + lane;
    int row = s >> 3;
    int u = (s & 7) ^ (row & 7);
    gB[r] = (size_t)(o0 + row) * K + u * 8;
    lBh[r] = Bh + (size_t)(wave * 128 + r * 64) * 8;
    lBl[r] = Bl + (size_t)(wave * 128 + r * 64) * 8;
  }

  // A direct-from-global fragment pointers: row = qm*64+i*16+fr, k base q*8
  const ushort_t* aptr[4];
#pragma unroll
  for (int i = 0; i < 4; ++i)
    aptr[i] = A + (size_t)(m0 + qm * 64 + i * 16 + fr) * K + q * 8;

  // B frag LDS offsets (swizzled), per kk half
  int boff[2][2];
#pragma unroll
  for (int j = 0; j < 2; ++j)
#pragma unroll
    for (int kk = 0; kk < 2; ++kk) {
      int row = qn * 32 + j * 16 + fr;
      boff[j][kk] = row * 64 + (((kk * 4 + q) ^ (row & 7))) * 8;
    }

  for (int kc = 0; kc < K; kc += 64) {
    // A frags: direct global loads (in flight alongside glds16; the barrier's
    // vmcnt(0) drain is exactly the dependency we need before MFMA)
    bf16x8 af[4][2];
#pragma unroll
    for (int i = 0; i < 4; ++i)
#pragma unroll
      for (int kk = 0; kk < 2; ++kk)
        af[i][kk] = *(const bf16x8*)(aptr[i] + kc + kk * 32);
#pragma unroll
    for (int r = 0; r < 2; ++r) {
      glds16(Bhi + gB[r] + kc, lBh[r]);
      glds16(Blo + gB[r] + kc, lBl[r]);
    }
    __syncthreads();

#pragma unroll
    for (int kk = 0; kk < 2; ++kk) {
      bf16x8 bh[2], bl[2];
#pragma unroll
      for (int j = 0; j < 2; ++j) {
        bh[j] = *(const bf16x8*)(Bh + boff[j][kk]);
        bl[j] = *(const bf16x8*)(Bl + boff[j][kk]);
      }
#pragma unroll
      for (int i = 0; i < 4; ++i)
#pragma unroll
        for (int j = 0; j < 2; ++j) {
          acc[i][j] = __builtin_amdgcn_mfma_f32_16x16x32_bf16(af[i][kk], bh[j], acc[i][j], 0, 0, 0);
          acc[i][j] = __builtin_amdgcn_mfma_f32_16x16x32_bf16(af[i][kk], bl[j], acc[i][j], 0, 0, 0);
        }
    }
    __syncthreads();
  }

  // acc -> LDS Z-tile: t = qm*64+i*16+q*4+rr, o-local = qn*32+j*16+fr
#pragma unroll
  for (int i = 0; i < 4; ++i)
#pragma unroll
    for (int j = 0; j < 2; ++j)
#pragma unroll
      for (int rr = 0; rr < 4; ++rr)
        Zt[(qm * 64 + i * 16 + q * 4 + rr) * 65 + qn * 32 + j * 16 + fr] = acc[i][j][rr];
  __syncthreads();

  // fused leaky-IF scan: thread tid<64 owns o-column (o0+tid)
  if (tid < 64) {
#pragma clang fp contract(off)
    float cur = 0.0f, vol = 0.0f;
    const int o = o0 + tid;
    for (int t = 0; t < 128; ++t) {
      float z = Zt[t * 65 + tid];
      cur = cur * 0.7f;
      cur = cur + z;
      vol = vol * 0.2f;
      vol = vol + cur;
      float v = vol - 1.0f;
      float s = (v >= 0.0f) ? 1.0f : 0.0f;
      vol = vol * (1.0f - s);
      S[(size_t)(m0 + t) * O_TOT + o] = (v >= 0.0f) ? 0x3F80u : 0u;
    }
  }
}

// ---------- layer 3 fused: per-b dense (O=2, fp32) + scan + output ----------
__global__ __launch_bounds__(256) void gemm3_scan(const ushort_t* __restrict__ X,
                                                  const float* __restrict__ W3,
                                                  float* __restrict__ out) {
  __shared__ float w3s[2048];
  __shared__ float z3[256];  // [t*2 + o]
  __shared__ float sp[256];  // [o*128 + t]
  const int tid = threadIdx.x;
  const int b = blockIdx.x;
  for (int i = tid; i < 2048; i += 256) w3s[i] = W3[i];
  __syncthreads();
  const int wave = tid >> 6, lane = tid & 63;
  for (int tt = 0; tt < 32; ++tt) {
    int t = wave * 32 + tt;
    const uint_t* row = (const uint_t*)(X + (size_t)(b * 128 + t) * 1024) + lane * 8;
    float s0 = 0.0f, s1 = 0.0f;
#pragma unroll
    for (int jw = 0; jw < 8; ++jw) {
      uint_t u = row[jw];
      float x0 = __uint_as_float(u << 16);
      float x1 = __uint_as_float(u & 0xFFFF0000u);
      int i0 = lane * 16 + jw * 2;
      s0 = fmaf(x0, w3s[i0], s0);
      s1 = fmaf(x0, w3s[1024 + i0], s1);
      s0 = fmaf(x1, w3s[i0 + 1], s0);
      s1 = fmaf(x1, w3s[1024 + i0 + 1], s1);
    }
#pragma unroll
    for (int off = 32; off > 0; off >>= 1) {
      s0 += __shfl_down(s0, off);
      s1 += __shfl_down(s1, off);
    }
    if (lane == 0) {
      z3[t * 2] = s0;
      z3[t * 2 + 1] = s1;
    }
  }
  __syncthreads();
  if (tid < 2) {
#pragma clang fp contract(off)
    float cur = 0.0f, vol = 0.0f;
    for (int t = 0; t < 128; ++t) {
      float z = z3[t * 2 + tid];
      cur = cur * 0.7f;
      cur = cur + z;
      vol = vol * 0.2f;
      vol = vol + cur;
      float v = vol - 1.0f;
      float s = (v >= 0.0f) ? 1.0f : 0.0f;
      vol = vol * (1.0f - s);
      sp[tid * 128 + t] = s;
    }
  }
  __syncthreads();
  out[b * 256 + tid] = sp[tid];
}

extern "C" void kernel_launch(void* const* d_in, const int* in_sizes, int n_in,
                              void* d_out, int out_size, void* d_ws, size_t ws_size,
                              hipStream_t stream) {
  const float* spike = (const float*)d_in[0];  // [64, 2048, 128]
  const float* W1 = (const float*)d_in[1];     // [1024, 2048]
  const float* W2 = (const float*)d_in[2];     // [1024, 1024]
  const float* W3 = (const float*)d_in[3];     // [2, 1024]
  float* out = (float*)d_out;                  // [64, 2, 128]

  char* ws = (char*)d_ws;
  ushort_t* A1 = (ushort_t*)ws;                                 // 32 MB
  ushort_t* S2 = (ushort_t*)(ws + (size_t)32 * 1024 * 1024);    // 16 MB
  ushort_t* S3 = (ushort_t*)(ws + (size_t)48 * 1024 * 1024);    // 16 MB
  ushort_t* W1hi = (ushort_t*)(ws + (size_t)64 * 1024 * 1024);  // 4 MB
  ushort_t* W1lo = (ushort_t*)(ws + (size_t)68 * 1024 * 1024);  // 4 MB
  ushort_t* W2hi = (ushort_t*)(ws + (size_t)72 * 1024 * 1024);  // 2 MB
  ushort_t* W2lo = (ushort_t*)(ws + (size_t)74 * 1024 * 1024);  // 2 MB

  // blocks 0..12287: W split; 12288..13311: spike transpose (64 b x 16 i-tiles)
  prep<<<13312, 256, 0, stream>>>(W1, W2, spike, W1hi, W1lo, W2hi, W2lo, A1);
  // L1: M=8192 (b*128+t), K=2048, O=1024
  gemm_scan<<<dim3(16, 64), 256, 0, stream>>>(A1, W1hi, W1lo, S2, 2048);
  // L2: K=1024
  gemm_scan<<<dim3(16, 64), 256, 0, stream>>>(S2, W2hi, W2lo, S3, 1024);
  // L3 + final scan + output
  gemm3_scan<<<64, 256, 0, stream>>>(S3, W3, out);
}

// Round 10
// 251.526 us; speedup vs baseline: 1.4270x; 1.4270x over previous
//
#include <hip/hip_runtime.h>

// SLAYER 3-layer CUBA SNN — fused MFMA GEMM + leaky-IF scan (4 launches).
// R10: B (weight) planes are PRE-PACKED in MFMA fragment order during prep,
// so the GEMM loads B frags directly global->register with wave-contiguous
// 1KB reads (R9's failure was scattered per-lane loads; packed layout fixes
// coalescing). B no longer touches LDS: LDS traffic per chunk-block drops
// 96 KB -> 48 KB (A stage 16K + A frag reads 32K) — LDS was the binding pipe
// at MfmaUtil 41%. A path identical to proven R7 (glds16 + XOR swizzle).
// Packed layout per plane: P[o_blk][kc64][qn][j][kk][q][fr][e], so lane
// (q*16+fr) reading 8 elems at offset lane*8 is contiguous per (qn,j,kk).
// Weights: W = hi + lo bf16 planes; spikes exact in bf16 (absmax 0.0 R3-R8).
// Layout m = b*128 + t: block holds full Z[t][o] history -> in-LDS scan.

typedef unsigned short ushort_t;
typedef unsigned int uint_t;
typedef __bf16 bf16x8 __attribute__((ext_vector_type(8)));
typedef float f32x4 __attribute__((ext_vector_type(4)));

#define O_TOT 1024

__device__ __forceinline__ void glds16(const ushort_t* g, ushort_t* l) {
  __builtin_amdgcn_global_load_lds(
      (const __attribute__((address_space(1))) uint_t*)g,
      (__attribute__((address_space(3))) uint_t*)l, 16, 0, 0);
}

__device__ __forceinline__ ushort_t f32_to_bf16_rne(float f) {
  uint_t u = __float_as_uint(f);
  u += 0x7FFFu + ((u >> 16) & 1u);
  return (ushort_t)(u >> 16);
}

// ---- prep: W1/W2 split+pack into fragment order, + spike transpose ---------
// packed idx = ((o_blk*(K/64)+kc)*4096) + qn*2048 + j*1024 + kk*512 + q*128
//              + fr*8 + e;  o = o_blk*64+qn*32+j*16+fr, k = kc*64+kk*32+q*8+e.
__global__ __launch_bounds__(256) void prep(const float* __restrict__ W1,
                                            const float* __restrict__ W2,
                                            const float* __restrict__ spike,
                                            ushort_t* __restrict__ h1,
                                            ushort_t* __restrict__ l1,
                                            ushort_t* __restrict__ h2,
                                            ushort_t* __restrict__ l2,
                                            ushort_t* __restrict__ A1) {
  const int tid = threadIdx.x;
  if (blockIdx.x < 12288) {
    const float* W;
    ushort_t *hp, *lp;
    int idx, K;
    if (blockIdx.x < 8192) {  // W1: K=2048, K/64=32
      idx = blockIdx.x * 256 + tid;
      W = W1; hp = h1; lp = l1; K = 2048;
    } else {                  // W2: K=1024, K/64=16
      idx = (blockIdx.x - 8192) * 256 + tid;
      W = W2; hp = h2; lp = l2; K = 1024;
    }
    int e = idx & 7, fr = (idx >> 3) & 15, q = (idx >> 7) & 3;
    int kk = (idx >> 9) & 1, j = (idx >> 10) & 1, qn = (idx >> 11) & 1;
    int rest = idx >> 12;
    int kcm = (K == 2048) ? 31 : 15;
    int kcs = (K == 2048) ? 5 : 4;
    int kc = rest & kcm, o_blk = rest >> kcs;
    int o = o_blk * 64 + qn * 32 + j * 16 + fr;
    int k = kc * 64 + kk * 32 + q * 8 + e;
    float w = W[(size_t)o * K + k];
    ushort_t h = f32_to_bf16_rne(w);
    hp[idx] = h;
    lp[idx] = f32_to_bf16_rne(w - __uint_as_float(((uint_t)h) << 16));
    return;
  }
  __shared__ ushort_t lds[128 * 130];  // [i][t] padded, 33,280 B
  const int bid = blockIdx.x - 12288;  // 0..1023
  const int b = bid >> 4;
  const int i0 = (bid & 15) * 128;
#pragma unroll
  for (int it = 0; it < 16; ++it) {
    int p = it * 256 + tid;
    int i = p >> 5, tg = (p & 31) * 4;
    float4 v = *(const float4*)(spike + ((size_t)b * 2048 + i0 + i) * 128 + tg);
    lds[i * 130 + tg + 0] = (v.x != 0.0f) ? 0x3F80u : 0u;
    lds[i * 130 + tg + 1] = (v.y != 0.0f) ? 0x3F80u : 0u;
    lds[i * 130 + tg + 2] = (v.z != 0.0f) ? 0x3F80u : 0u;
    lds[i * 130 + tg + 3] = (v.w != 0.0f) ? 0x3F80u : 0u;
  }
  __syncthreads();
#pragma unroll
  for (int it = 0; it < 16; ++it) {
    int p = it * 256 + tid;
    int t = p >> 5, j = p & 31;  // j: uint2 index (4 ushorts)
    uint_t u0 = (uint_t)lds[(4 * j + 0) * 130 + t] | ((uint_t)lds[(4 * j + 1) * 130 + t] << 16);
    uint_t u1 = (uint_t)lds[(4 * j + 2) * 130 + t] | ((uint_t)lds[(4 * j + 3) * 130 + t] << 16);
    uint2* dst = (uint2*)(A1 + (size_t)(b * 128 + t) * 2048 + i0);
    dst[j] = make_uint2(u0, u1);
  }
}

// ------- fused GEMM (128m x 64o tile, kc64, hi/lo bf16) + scan --------------
// A staged in LDS (XOR slot swizzle, proven R7); B frags loaded directly
// from packed global (1KB contiguous per wave instruction, L2-resident).
__global__ __launch_bounds__(256, 4)
void gemm_scan(const ushort_t* __restrict__ A, const ushort_t* __restrict__ Bhp,
               const ushort_t* __restrict__ Blp, ushort_t* __restrict__ S,
               int K) {
  __shared__ float smemf[128 * 65];  // 33,280 B (Zt epilogue overlay)
  ushort_t* As = (ushort_t*)smemf;   // 128 x 64 k (16 KB)
  float* Zt = smemf;                 // [128 t][65]

  const int tid = threadIdx.x;
  const int wave = tid >> 6, lane = tid & 63;
  const int b = blockIdx.y;
  const int m0 = b * 128;
  const int o0 = blockIdx.x * 64;
  const int qm = wave >> 1, qn = wave & 1;
  const int fr = lane & 15, q = lane >> 4;

  f32x4 acc[4][2];
#pragma unroll
  for (int i = 0; i < 4; ++i)
#pragma unroll
    for (int j = 0; j < 2; ++j) acc[i][j] = (f32x4){0.f, 0.f, 0.f, 0.f};

  // A staging: 1024 slots, 4 rounds/wave (XOR slot swizzle)
  size_t gA[4];
  ushort_t* lA[4];
#pragma unroll
  for (int r = 0; r < 4; ++r) {
    int s = wave * 256 + r * 64 + lane;
    int row = s >> 3;
    int u = (s & 7) ^ (row & 7);
    gA[r] = (size_t)(m0 + row) * K + u * 8;
    lA[r] = As + (size_t)(wave * 256 + r * 64) * 8;
  }

  // A frag LDS offsets (swizzled), per kk half
  int aoff[4][2];
#pragma unroll
  for (int i = 0; i < 4; ++i)
#pragma unroll
    for (int kk = 0; kk < 2; ++kk) {
      int row = qm * 64 + i * 16 + fr;
      aoff[i][kk] = row * 64 + (((kk * 4 + q) ^ (row & 7))) * 8;
    }

  // packed B base for this block/wave/lane (o_blk = blockIdx.x)
  const size_t pbase = ((size_t)blockIdx.x * (K >> 6)) * 4096 + qn * 2048 + lane * 8;
  const ushort_t* pBh = Bhp + pbase;
  const ushort_t* pBl = Blp + pbase;

  for (int kc = 0; kc < K; kc += 64) {
    // B frags: coalesced global loads (issued first; drained by the barrier)
    bf16x8 bh[2][2], bl[2][2];
    const ushort_t* ph = pBh + (size_t)(kc >> 6) * 4096;
    const ushort_t* pl = pBl + (size_t)(kc >> 6) * 4096;
#pragma unroll
    for (int j = 0; j < 2; ++j)
#pragma unroll
      for (int kk = 0; kk < 2; ++kk) {
        bh[j][kk] = *(const bf16x8*)(ph + j * 1024 + kk * 512);
        bl[j][kk] = *(const bf16x8*)(pl + j * 1024 + kk * 512);
      }
#pragma unroll
    for (int r = 0; r < 4; ++r) glds16(A + gA[r] + kc, lA[r]);
    __syncthreads();

#pragma unroll
    for (int kk = 0; kk < 2; ++kk) {
      bf16x8 af[4];
#pragma unroll
      for (int i = 0; i < 4; ++i) af[i] = *(const bf16x8*)(As + aoff[i][kk]);
#pragma unroll
      for (int i = 0; i < 4; ++i)
#pragma unroll
        for (int j = 0; j < 2; ++j) {
          acc[i][j] = __builtin_amdgcn_mfma_f32_16x16x32_bf16(af[i], bh[j][kk], acc[i][j], 0, 0, 0);
          acc[i][j] = __builtin_amdgcn_mfma_f32_16x16x32_bf16(af[i], bl[j][kk], acc[i][j], 0, 0, 0);
        }
    }
    __syncthreads();
  }

  // acc -> LDS Z-tile: t = qm*64+i*16+q*4+rr, o-local = qn*32+j*16+fr
#pragma unroll
  for (int i = 0; i < 4; ++i)
#pragma unroll
    for (int j = 0; j < 2; ++j)
#pragma unroll
      for (int rr = 0; rr < 4; ++rr)
        Zt[(qm * 64 + i * 16 + q * 4 + rr) * 65 + qn * 32 + j * 16 + fr] = acc[i][j][rr];
  __syncthreads();

  // fused leaky-IF scan: thread tid<64 owns o-column (o0+tid)
  if (tid < 64) {
#pragma clang fp contract(off)
    float cur = 0.0f, vol = 0.0f;
    const int o = o0 + tid;
    for (int t = 0; t < 128; ++t) {
      float z = Zt[t * 65 + tid];
      cur = cur * 0.7f;
      cur = cur + z;
      vol = vol * 0.2f;
      vol = vol + cur;
      float v = vol - 1.0f;
      float s = (v >= 0.0f) ? 1.0f : 0.0f;
      vol = vol * (1.0f - s);
      S[(size_t)(m0 + t) * O_TOT + o] = (v >= 0.0f) ? 0x3F80u : 0u;
    }
  }
}

// ---------- layer 3 fused: per-b dense (O=2, fp32) + scan + output ----------
__global__ __launch_bounds__(256) void gemm3_scan(const ushort_t* __restrict__ X,
                                                  const float* __restrict__ W3,
                                                  float* __restrict__ out) {
  __shared__ float w3s[2048];
  __shared__ float z3[256];  // [t*2 + o]
  __shared__ float sp[256];  // [o*128 + t]
  const int tid = threadIdx.x;
  const int b = blockIdx.x;
  for (int i = tid; i < 2048; i += 256) w3s[i] = W3[i];
  __syncthreads();
  const int wave = tid >> 6, lane = tid & 63;
  for (int tt = 0; tt < 32; ++tt) {
    int t = wave * 32 + tt;
    const uint_t* row = (const uint_t*)(X + (size_t)(b * 128 + t) * 1024) + lane * 8;
    float s0 = 0.0f, s1 = 0.0f;
#pragma unroll
    for (int jw = 0; jw < 8; ++jw) {
      uint_t u = row[jw];
      float x0 = __uint_as_float(u << 16);
      float x1 = __uint_as_float(u & 0xFFFF0000u);
      int i0 = lane * 16 + jw * 2;
      s0 = fmaf(x0, w3s[i0], s0);
      s1 = fmaf(x0, w3s[1024 + i0], s1);
      s0 = fmaf(x1, w3s[i0 + 1], s0);
      s1 = fmaf(x1, w3s[1024 + i0 + 1], s1);
    }
#pragma unroll
    for (int off = 32; off > 0; off >>= 1) {
      s0 += __shfl_down(s0, off);
      s1 += __shfl_down(s1, off);
    }
    if (lane == 0) {
      z3[t * 2] = s0;
      z3[t * 2 + 1] = s1;
    }
  }
  __syncthreads();
  if (tid < 2) {
#pragma clang fp contract(off)
    float cur = 0.0f, vol = 0.0f;
    for (int t = 0; t < 128; ++t) {
      float z = z3[t * 2 + tid];
      cur = cur * 0.7f;
      cur = cur + z;
      vol = vol * 0.2f;
      vol = vol + cur;
      float v = vol - 1.0f;
      float s = (v >= 0.0f) ? 1.0f : 0.0f;
      vol = vol * (1.0f - s);
      sp[tid * 128 + t] = s;
    }
  }
  __syncthreads();
  out[b * 256 + tid] = sp[tid];
}

extern "C" void kernel_launch(void* const* d_in, const int* in_sizes, int n_in,
                              void* d_out, int out_size, void* d_ws, size_t ws_size,
                              hipStream_t stream) {
  const float* spike = (const float*)d_in[0];  // [64, 2048, 128]
  const float* W1 = (const float*)d_in[1];     // [1024, 2048]
  const float* W2 = (const float*)d_in[2];     // [1024, 1024]
  const float* W3 = (const float*)d_in[3];     // [2, 1024]
  float* out = (float*)d_out;                  // [64, 2, 128]

  char* ws = (char*)d_ws;
  ushort_t* A1 = (ushort_t*)ws;                                 // 32 MB
  ushort_t* S2 = (ushort_t*)(ws + (size_t)32 * 1024 * 1024);    // 16 MB
  ushort_t* S3 = (ushort_t*)(ws + (size_t)48 * 1024 * 1024);    // 16 MB
  ushort_t* W1hi = (ushort_t*)(ws + (size_t)64 * 1024 * 1024);  // 4 MB packed
  ushort_t* W1lo = (ushort_t*)(ws + (size_t)68 * 1024 * 1024);  // 4 MB packed
  ushort_t* W2hi = (ushort_t*)(ws + (size_t)72 * 1024 * 1024);  // 2 MB packed
  ushort_t* W2lo = (ushort_t*)(ws + (size_t)74 * 1024 * 1024);  // 2 MB packed

  // blocks 0..8191: W1 pack; 8192..12287: W2 pack; 12288..13311: transpose
  prep<<<13312, 256, 0, stream>>>(W1, W2, spike, W1hi, W1lo, W2hi, W2lo, A1);
  // L1: M=8192 (b*128+t), K=2048, O=1024
  gemm_scan<<<dim3(16, 64), 256, 0, stream>>>(A1, W1hi, W1lo, S2, 2048);
  // L2: K=1024
  gemm_scan<<<dim3(16, 64), 256, 0, stream>>>(S2, W2hi, W2lo, S3, 1024);
  // L3 + final scan + output
  gemm3_scan<<<64, 256, 0, stream>>>(S3, W3, out);
}